// Round 7
// baseline (235.096 us; speedup 1.0000x reference)
//
#include <hip/hip_runtime.h>

#define IN_CH 256
#define IMG_W 56
#define CHF   3136               // 56*56 floats per channel image
typedef float f4 __attribute__((ext_vector_type(4)));

// out[b,c0] = conv3x3(x[b,c0], w[2c0]) + conv3x3(x[b,c1], w[2c1+1])
// out[b,c1] = conv3x3(x[b,c1], w[2c1]) + conv3x3(x[b,c0], w[2c0+1]),  c1 = c0^4
//
// PERSISTENT PIPELINED WAVES. 4096 waves total (1024 blk x 4 waves) -- exactly
// resident at 4 blk/CU. Job = (pair, batch, row-quad): 128*32*7 = 28672 = 4096*7,
// so each wave runs EXACTLY 7 jobs, double-buffered in registers: job t+1's
// 8 float4 loads (and next weights, SGPR) are in flight under job t's 288 FMAs.
// Waves issue loads continuously for their entire life -- no one-shot
// {load, stall, compute, die} lifecycle (the R2-R6 invariant).
// Wave layout: 56 active lanes = 4 row-pairs x 14 col-strips; side-halo columns
// come from __shfl of neighbor lanes (no scalar edge loads).
__global__ __launch_bounds__(256, 4) void dwconv_butterfly(
    const float* __restrict__ x, const float* __restrict__ wgt,
    float* __restrict__ out)
{
    const int lane = threadIdx.x & 63;
    const int widx = __builtin_amdgcn_readfirstlane(threadIdx.x >> 6);
    const int gw   = blockIdx.x * 4 + widx;        // 0..4095
    const int r    = lane / 14;                    // row-pair in quad (0..3; 4 = idle)
    const int s    = lane - r * 14;                // col strip 0..13
    const bool act   = lane < 56;
    const int  w0    = 4 * s;
    const bool has_l = (s > 0), has_r = (s < 13);

    // ---- load stage: fill one register window + one SGPR weight set ----
    auto LOAD = [&](int t, f4* va, f4* vb, float* w4) {
        const int jt = gw + 4096 * t;              // job id
        const int q  = jt % 7;                     // row-quad 0..6
        const int pb = jt / 7;
        const int p  = pb & 127;
        const int b  = pb >> 7;
        const int c0 = ((p >> 2) << 3) | (p & 3);  // bit2 == 0
        const int c1 = c0 ^ 4;
        const float* x0 = x + ((size_t)b * IN_CH + c0) * CHF;
        const float* x1 = x + ((size_t)b * IN_CH + c1) * CHF;
        const int brow = 8 * q + 2 * r - 1;        // input row of tap k=0
        if (act) {
#pragma unroll
            for (int k = 0; k < 4; ++k) {
                const int ir  = brow + k;
                const int irc = ir < 0 ? 0 : (ir > 55 ? 55 : ir);   // clamped, masked later
                va[k] = *(const f4*)(x0 + irc * IMG_W + w0);        // 16B aligned
                vb[k] = *(const f4*)(x1 + irc * IMG_W + w0);
            }
        }
        // weights: wave-uniform pointers (scalar chain) -> s_loads into SGPRs
        const float* pa = wgt + (size_t)(2 * c0) * 9;       // out c0 <- x c0
        const float* pq = wgt + (size_t)(2 * c1 + 1) * 9;   // out c0 <- x c1
        const float* pc = wgt + (size_t)(2 * c1) * 9;       // out c1 <- x c1
        const float* pd = wgt + (size_t)(2 * c0 + 1) * 9;   // out c1 <- x c0
#pragma unroll
        for (int i = 0; i < 9; ++i) {
            w4[i] = pa[i]; w4[9 + i] = pq[i]; w4[18 + i] = pc[i]; w4[27 + i] = pd[i];
        }
    };

    // ---- compute stage: halo via shfl, mask, 288 FMA, 4 float4 stores ----
    auto COMPUTE = [&](int t, f4* va, f4* vb, const float* w4) {
        const int jt = gw + 4096 * t;
        const int q  = jt % 7;
        const int pb = jt / 7;
        const int p  = pb & 127;
        const int b  = pb >> 7;
        const int c0 = ((p >> 2) << 3) | (p & 3);
        const int c1 = c0 ^ 4;
        float* o0 = out + ((size_t)b * IN_CH + c0) * CHF;
        float* o1 = out + ((size_t)b * IN_CH + c1) * CHF;
        const int brow = 8 * q + 2 * r - 1;

        float acc[2][8];                  // [out row j][ch*4 + i]
#pragma unroll
        for (int j = 0; j < 2; ++j)
#pragma unroll
            for (int i = 0; i < 8; ++i) acc[j][i] = 0.f;

#pragma unroll
        for (int k = 0; k < 4; ++k) {
            const bool rvk = (unsigned)(brow + k) < 56u;
            // neighbor-lane halo: lane-1 holds cols w0-4..w0-1 (.w), lane+1 holds w0+4 (.x)
            const float lA = __shfl_up(va[k].w, 1);
            const float rA = __shfl_down(va[k].x, 1);
            const float lB = __shfl_up(vb[k].w, 1);
            const float rB = __shfl_down(vb[k].x, 1);
            float W0[6], W1[6];           // cols w0-1 .. w0+4
            W0[0] = (rvk && has_l) ? lA : 0.f;
            W0[1] = rvk ? va[k].x : 0.f;
            W0[2] = rvk ? va[k].y : 0.f;
            W0[3] = rvk ? va[k].z : 0.f;
            W0[4] = rvk ? va[k].w : 0.f;
            W0[5] = (rvk && has_r) ? rA : 0.f;
            W1[0] = (rvk && has_l) ? lB : 0.f;
            W1[1] = rvk ? vb[k].x : 0.f;
            W1[2] = rvk ? vb[k].y : 0.f;
            W1[3] = rvk ? vb[k].z : 0.f;
            W1[4] = rvk ? vb[k].w : 0.f;
            W1[5] = (rvk && has_r) ? rB : 0.f;
            // tap k serves out row j with kernel row kh = k - j (0..2)
#pragma unroll
            for (int j = 0; j < 2; ++j) {
                const int kh = k - j;
                if (kh < 0 || kh > 2) continue;
#pragma unroll
                for (int kw = 0; kw < 3; ++kw) {
                    const float fa = w4[kh * 3 + kw];
                    const float fb = w4[9 + kh * 3 + kw];
                    const float fc = w4[18 + kh * 3 + kw];
                    const float fd = w4[27 + kh * 3 + kw];
#pragma unroll
                    for (int i = 0; i < 4; ++i) {
                        const float u0 = W0[i + kw];
                        const float u1 = W1[i + kw];
                        acc[0 + j][i]     += u0 * fa + u1 * fb;
                        acc[0 + j][4 + i] += u1 * fc + u0 * fd;
                    }
                }
            }
        }

        if (act) {
#pragma unroll
            for (int j = 0; j < 2; ++j) {
                const int orow = 8 * q + 2 * r + j;
                f4 v0; v0.x = acc[j][0]; v0.y = acc[j][1]; v0.z = acc[j][2]; v0.w = acc[j][3];
                f4 v1; v1.x = acc[j][4]; v1.y = acc[j][5]; v1.z = acc[j][6]; v1.w = acc[j][7];
                *(f4*)(o0 + orow * IMG_W + w0) = v0;
                *(f4*)(o1 + orow * IMG_W + w0) = v1;
            }
        }
    };

    // ---- 7-job pipeline, register double-buffered (all indices static) ----
    f4    vaA[4], vbA[4], vaB[4], vbB[4];
    float wA[36], wB[36];

    LOAD(0, vaA, vbA, wA);
#pragma unroll
    for (int t = 0; t < 7; ++t) {
        if ((t & 1) == 0) {
            if (t < 6) LOAD(t + 1, vaB, vbB, wB);
            COMPUTE(t, vaA, vbA, wA);
        } else {
            if (t < 6) LOAD(t + 1, vaA, vbA, wA);
            COMPUTE(t, vaB, vbB, wB);
        }
    }
}

extern "C" void kernel_launch(void* const* d_in, const int* in_sizes, int n_in,
                              void* d_out, int out_size, void* d_ws, size_t ws_size,
                              hipStream_t stream) {
    const float* x = (const float*)d_in[0];   // (32, 256, 56, 56) fp32
    const float* w = (const float*)d_in[1];   // (512, 1, 3, 3)   fp32
    float* out = (float*)d_out;               // (32, 256, 56, 56) fp32

    dim3 grid(1024);        // 4096 waves == exactly-resident persistent grid
    dim3 block(256);
    dwconv_butterfly<<<grid, block, 0, stream>>>(x, w, out);
}